// Round 16
// baseline (542.729 us; speedup 1.0000x reference)
//
#include <hip/hip_runtime.h>
#include <hip/hip_bf16.h>
#include <stdint.h>

// ====== MEASUREMENT ROUND: all five kernels amplified x8 (revert next) ======

typedef __bf16 bf16x8 __attribute__((ext_vector_type(8)));
typedef float f32x4 __attribute__((ext_vector_type(4)));

#define KDIM 256
#define NPIX 16384
#define QKVS 768
#define REPS 8

__device__ __forceinline__ float b2f(ushort u){
    union { float f; uint32_t i; } x; x.i = ((uint32_t)u) << 16; return x.f;
}
__device__ __forceinline__ ushort f2b(float f){
    uint32_t u = __float_as_uint(f);
    uint32_t r = (u + 0x7fffu + ((u >> 16) & 1u)) >> 16;
    return (ushort)r;
}
__device__ __forceinline__ void unpack2(uint d, float& lo, float& hi){
    lo = __uint_as_float(d << 16);
    hi = __uint_as_float(d & 0xffff0000u);
}
__device__ __forceinline__ uint cvtpk(float lo, float hi){
    uint r;
    asm volatile("v_cvt_pk_bf16_f32 %0, %1, %2" : "=v"(r) : "v"(lo), "v"(hi));
    return r;
}

// --------- P1: single x pass -> bf16 CL transpose + fp32 LN partials --------
__global__ __launch_bounds__(256)
void ln_fuse(const float* __restrict__ x, ushort* __restrict__ xt,
             float* __restrict__ psum, float* __restrict__ psum2){
    __shared__ ushort sh[128 * 68];
    __shared__ float ssum[16 * 132], ssum2[16 * 132];
    const int bid = blockIdx.x;
    const int b = bid >> 7, rem = bid & 127, h = rem >> 1, ch = (rem & 1) * 128;
    const int tid = threadIdx.x;
    const int csub = tid >> 4, w4 = tid & 15;
#pragma unroll 1
    for (int rep = 0; rep < REPS; ++rep){
        asm volatile("" ::: "memory");
#pragma unroll
        for (int i = 0; i < 8; ++i){
            int c = csub + 16 * i;
            float4 v = *(const float4*)(x + ((size_t)(b * 256 + ch + c)) * 4096
                                          + h * 64 + w4 * 4);
            ushort4 u; u.x = f2b(v.x); u.y = f2b(v.y); u.z = f2b(v.z); u.w = f2b(v.w);
            *(ushort4*)&sh[c * 68 + w4 * 4] = u;
            ssum [w4 * 132 + c] = v.x + v.y + v.z + v.w;
            ssum2[w4 * 132 + c] = v.x * v.x + v.y * v.y + v.z * v.z + v.w * v.w;
        }
        __syncthreads();
        if (tid < 128){
            float S = 0.f, S2 = 0.f;
#pragma unroll
            for (int j = 0; j < 16; ++j){ S += ssum[j * 132 + tid]; S2 += ssum2[j * 132 + tid]; }
            psum [(b * 64 + h) * 256 + ch + tid] = S;
            psum2[(b * 64 + h) * 256 + ch + tid] = S2;
        }
        const int c16 = tid & 15, w16 = tid >> 4;
#pragma unroll
        for (int p = 0; p < 4; ++p){
            int w = p * 16 + w16;
            union { ushort u[8]; uint4 v; } r;
#pragma unroll
            for (int j = 0; j < 8; ++j) r.u[j] = sh[(c16 * 8 + j) * 68 + w];
            size_t row = (size_t)(b * 4096 + h * 64 + w);
            *(uint4*)(xt + row * 256 + ch + c16 * 8) = r.v;
        }
        __syncthreads();
    }
}

// --------- P2: per-b scaled weights + folded bias + pad row (block-range) ---
__global__ __launch_bounds__(256)
void prep2(const float* __restrict__ Wq, const float* __restrict__ bq,
           const float* __restrict__ Wk, const float* __restrict__ bk,
           const float* __restrict__ Wv, const float* __restrict__ bv,
           const float* __restrict__ Wo,
           const float* __restrict__ psum, const float* __restrict__ psum2,
           ushort* __restrict__ wtq, ushort* __restrict__ wot,
           float* __restrict__ biasp, ushort* __restrict__ qkv){
    __shared__ float shW[32 * 33];
    __shared__ float shS[8 * 32], shS2[8 * 32], shRV[4 * 32], shM[256];
    const int bid = blockIdx.x, tid = threadIdx.x;
#pragma unroll 1
    for (int rep = 0; rep < REPS; ++rep){
        asm volatile("" ::: "memory");
        if (bid < 192){
            int mat = bid / 64, tile = bid % 64;
            int ti = tile & 7, tj = tile >> 3;
            {
                int kk = tid & 31, idx = tid >> 5;
                int b = idx >> 1, h0 = (idx & 1) * 32;
                float S = 0.f, S2 = 0.f;
                for (int r = 0; r < 32; ++r){
                    int off = (b * 64 + h0 + r) * 256 + tj * 32 + kk;
                    S += psum[off]; S2 += psum2[off];
                }
                shS[idx * 32 + kk] = S; shS2[idx * 32 + kk] = S2;
            }
            __syncthreads();
            if (tid < 128){
                int b = tid >> 5, kk = tid & 31;
                float S  = shS [(b * 2) * 32 + kk] + shS [(b * 2 + 1) * 32 + kk];
                float S2 = shS2[(b * 2) * 32 + kk] + shS2[(b * 2 + 1) * 32 + kk];
                float m = S * (1.f / 4096.f);
                float v = S2 * (1.f / 4096.f) - m * m;
                shRV[b * 32 + kk] = rsqrtf(v + 1e-5f);
            }
            const float* src = (mat == 0) ? Wq : (mat == 1) ? Wk : Wv;
            float qs = (mat == 0) ? 0.0625f : 1.0f;
            int tx = tid & 31, ty = tid >> 5;
#pragma unroll
            for (int i = 0; i < 4; ++i)
                shW[(ty + i * 8) * 33 + tx] =
                    src[(size_t)(tj * 32 + ty + i * 8) * 256 + ti * 32 + tx] * qs;
            __syncthreads();
#pragma unroll
            for (int b = 0; b < 4; ++b){
                float rv = shRV[b * 32 + tx];
#pragma unroll
                for (int i = 0; i < 4; ++i){
                    int n = mat * 256 + ti * 32 + ty + i * 8;
                    wtq[((size_t)b * 768 + n) * 256 + tj * 32 + tx] =
                        f2b(shW[tx * 33 + ty + i * 8] * rv);
                }
            }
        } else if (bid < 256){
            int tile = bid - 192;
            int ti = tile & 7, tj = tile >> 3;
            int tx = tid & 31, ty = tid >> 5;
#pragma unroll
            for (int i = 0; i < 4; ++i)
                shW[(ty + i * 8) * 33 + tx] =
                    Wo[(size_t)(tj * 32 + ty + i * 8) * 256 + ti * 32 + tx];
            __syncthreads();
#pragma unroll
            for (int i = 0; i < 4; ++i)
                wot[(size_t)(ti * 32 + ty + i * 8) * 256 + tj * 32 + tx] =
                    f2b(shW[tx * 33 + ty + i * 8]);
        } else if (bid < 268){
            int t = bid - 256;
            int b = t / 3, mat = t % 3;
            float S = 0.f, S2 = 0.f;
            for (int h = 0; h < 64; ++h){
                S += psum[(b * 64 + h) * 256 + tid]; S2 += psum2[(b * 64 + h) * 256 + tid];
            }
            float m = S * (1.f / 4096.f);
            float v = S2 * (1.f / 4096.f) - m * m;
            shM[tid] = m * rsqrtf(v + 1e-5f);
            __syncthreads();
            const float* W  = (mat == 0) ? Wq : (mat == 1) ? Wk : Wv;
            const float* bb = (mat == 0) ? bq : (mat == 1) ? bk : bv;
            float qs = (mat == 0) ? 0.0625f : 1.0f;
            float acc = 0.f;
            for (int c = 0; c < 256; ++c)
                acc += shM[c] * W[(size_t)c * 256 + tid];
            biasp[b * 768 + mat * 256 + tid] = (bb[tid] - acc) * qs;
        } else {
            ushort* pad = qkv + (size_t)NPIX * QKVS;
            pad[tid]       = 0;
            pad[256 + tid] = f2b(bk[tid]);
            pad[512 + tid] = f2b(bv[tid]);
        }
        __syncthreads();
    }
}

// ---- QKV GEMM: 256x192 tile, BK=64, 8 waves, counted vmcnt, 256 blocks ----
__global__ __launch_bounds__(512, 1)
void gemm_qkv(const ushort* __restrict__ X, const ushort* __restrict__ Y,
              const float* __restrict__ bias, ushort* __restrict__ zb){
    __shared__ ushort ldsA[2][256 * 64];
    __shared__ ushort ldsB[2][192 * 64];
    const int tid  = threadIdx.x;
    const int lane = tid & 63;
    const int wid  = tid >> 6;
    const int wm   = wid >> 2;
    const int wn   = wid & 3;
    const int tile  = (blockIdx.x & 7) * 32 + (blockIdx.x >> 3);
    const int mtile = tile >> 2, ntile = tile & 3;
    const int x0 = mtile * 256, y0 = ntile * 192;
    const int bsel = x0 >> 12;
    const ushort* Yb   = Y + ((size_t)bsel * QKVS + y0) * 256;
    const float* biasb = bias + bsel * QKVS;

    auto stage = [&](int buf, int k0){
#pragma unroll
        for (int i = 0; i < 4; ++i){
            int f   = i * 512 + tid;
            int row = f >> 3, cp = f & 7;
            int cs  = cp ^ (row & 7);
            const ushort* ga = X + (size_t)(x0 + row) * KDIM + k0 + cs * 8;
            __builtin_amdgcn_global_load_lds(
                (const __attribute__((address_space(1))) void*)ga,
                (__attribute__((address_space(3))) void*)&ldsA[buf][f * 8], 16, 0, 0);
        }
#pragma unroll
        for (int i = 0; i < 3; ++i){
            int f   = i * 512 + tid;
            int row = f >> 3, cp = f & 7;
            int cs  = cp ^ (row & 7);
            const ushort* gb = Yb + (size_t)row * KDIM + k0 + cs * 8;
            __builtin_amdgcn_global_load_lds(
                (const __attribute__((address_space(1))) void*)gb,
                (__attribute__((address_space(3))) void*)&ldsB[buf][f * 8], 16, 0, 0);
        }
    };

#pragma unroll 1
    for (int rep = 0; rep < REPS; ++rep){
        asm volatile("" ::: "memory");
        f32x4 acc[8][3];
#pragma unroll
        for (int i = 0; i < 8; ++i)
#pragma unroll
            for (int j = 0; j < 3; ++j) acc[i][j] = f32x4{0.f, 0.f, 0.f, 0.f};

        stage(0, 0);
        stage(1, 64);
#pragma unroll
        for (int t = 0; t < 4; ++t){
            if (t < 3) asm volatile("s_waitcnt vmcnt(7)" ::: "memory");
            else       asm volatile("s_waitcnt vmcnt(0)" ::: "memory");
            __builtin_amdgcn_sched_barrier(0);
            __builtin_amdgcn_s_barrier();
            __builtin_amdgcn_sched_barrier(0);
            const int buf = t & 1;
            __builtin_amdgcn_s_setprio(1);
#pragma unroll
            for (int kk = 0; kk < 2; ++kk){
                bf16x8 af[8], bf[3];
#pragma unroll
                for (int fm = 0; fm < 8; ++fm){
                    int r = wm * 128 + fm * 16 + (lane & 15);
                    int c = kk * 4 + (lane >> 4);
                    af[fm] = *(const bf16x8*)&ldsA[buf][(r * 8 + (c ^ (r & 7))) * 8];
                }
#pragma unroll
                for (int fn = 0; fn < 3; ++fn){
                    int r = wn * 48 + fn * 16 + (lane & 15);
                    int c = kk * 4 + (lane >> 4);
                    bf[fn] = *(const bf16x8*)&ldsB[buf][(r * 8 + (c ^ (r & 7))) * 8];
                }
#pragma unroll
                for (int fm = 0; fm < 8; ++fm)
#pragma unroll
                    for (int fn = 0; fn < 3; ++fn)
                        acc[fm][fn] = __builtin_amdgcn_mfma_f32_16x16x32_bf16(
                            af[fm], bf[fn], acc[fm][fn], 0, 0, 0);
            }
            __builtin_amdgcn_s_setprio(0);
            __builtin_amdgcn_sched_barrier(0);
            __builtin_amdgcn_s_barrier();
            __builtin_amdgcn_sched_barrier(0);
            if (t < 2) stage(t & 1, (t + 2) * 64);
        }

#pragma unroll
        for (int fm = 0; fm < 8; ++fm){
#pragma unroll
            for (int fn = 0; fn < 3; ++fn){
                int xr = x0 + wm * 128 + fm * 16 + ((lane >> 4) << 2);
                int yc = y0 + wn * 48 + fn * 16 + (lane & 15);
                float bv = biasb[yc];
#pragma unroll
                for (int r = 0; r < 4; ++r)
                    zb[(size_t)(xr + r) * QKVS + yc] = f2b(acc[fm][fn][r] + bv);
            }
        }
        __syncthreads();
    }
}

// --------- 3x3 window attention: 16 lanes/pixel, 4x4 tiles, XCD swizzle -----
__global__ __launch_bounds__(256)
void attn_win(const ushort* __restrict__ qkv, ushort* __restrict__ ctx){
    const int tid = threadIdx.x;
    const int lane = tid & 63, wid = tid >> 6;
    const int l16 = lane & 15, pg = lane >> 4;
    const int obid = (blockIdx.x & 7) * 128 + (blockIdx.x >> 3);
    const int t = obid & 255, b = obid >> 8;
    const int tr = t >> 4, tc = t & 15;
    const int p = wid * 4 + pg;
    const int h = tr * 4 + (p >> 2), w = tc * 4 + (p & 3);
    const int pix = (b << 12) + (h << 6) + w;
    const uint PADOFF = (uint)NPIX * QKVS;
    const int cbase = l16 * 16;

#pragma unroll 1
    for (int rep = 0; rep < REPS; ++rep){
        asm volatile("" ::: "memory");
        const ushort* qp = qkv + (size_t)pix * QKVS + cbase;
        uint4 qa = *(const uint4*)qp;
        uint4 qb = *(const uint4*)(qp + 8);
        float qf[16];
        unpack2(qa.x, qf[0], qf[1]);  unpack2(qa.y, qf[2], qf[3]);
        unpack2(qa.z, qf[4], qf[5]);  unpack2(qa.w, qf[6], qf[7]);
        unpack2(qb.x, qf[8], qf[9]);  unpack2(qb.y, qf[10], qf[11]);
        unpack2(qb.z, qf[12], qf[13]); unpack2(qb.w, qf[14], qf[15]);

        float lg[9];
        uint roff[9];
#pragma unroll
        for (int n = 0; n < 9; ++n){
            int nh = h + n / 3 - 1, nw = w + n % 3 - 1;
            bool ok = ((unsigned)nh < 64u) & ((unsigned)nw < 64u);
            roff[n] = ok ? (uint)(((b << 12) + (nh << 6) + nw) * QKVS) : PADOFF;
            const ushort* kp = qkv + roff[n] + 256 + cbase;
            uint4 ka = *(const uint4*)kp;
            uint4 kb = *(const uint4*)(kp + 8);
            float kf[16];
            unpack2(ka.x, kf[0], kf[1]);  unpack2(ka.y, kf[2], kf[3]);
            unpack2(ka.z, kf[4], kf[5]);  unpack2(ka.w, kf[6], kf[7]);
            unpack2(kb.x, kf[8], kf[9]);  unpack2(kb.y, kf[10], kf[11]);
            unpack2(kb.z, kf[12], kf[13]); unpack2(kb.w, kf[14], kf[15]);
            float d = 0.f;
#pragma unroll
            for (int j = 0; j < 16; ++j) d += qf[j] * kf[j];
            d += __shfl_xor(d, 1); d += __shfl_xor(d, 2);
            d += __shfl_xor(d, 4); d += __shfl_xor(d, 8);
            lg[n] = d;
        }
        float m = lg[0];
#pragma unroll
        for (int n = 1; n < 9; ++n) m = fmaxf(m, lg[n]);
        float e[9], s = 0.f;
#pragma unroll
        for (int n = 0; n < 9; ++n){ e[n] = __expf(lg[n] - m); s += e[n]; }
        float inv = 1.f / s;

        float c[16];
#pragma unroll
        for (int j = 0; j < 16; ++j) c[j] = 0.f;
#pragma unroll
        for (int n = 0; n < 9; ++n){
            float a = e[n] * inv;
            const ushort* vp = qkv + roff[n] + 512 + cbase;
            uint4 va = *(const uint4*)vp;
            uint4 vb = *(const uint4*)(vp + 8);
            float vf[16];
            unpack2(va.x, vf[0], vf[1]);  unpack2(va.y, vf[2], vf[3]);
            unpack2(va.z, vf[4], vf[5]);  unpack2(va.w, vf[6], vf[7]);
            unpack2(vb.x, vf[8], vf[9]);  unpack2(vb.y, vf[10], vf[11]);
            unpack2(vb.z, vf[12], vf[13]); unpack2(vb.w, vf[14], vf[15]);
#pragma unroll
            for (int j = 0; j < 16; ++j) c[j] += a * vf[j];
        }
        uint4 oa, ob;
        oa.x = cvtpk(c[0], c[1]);   oa.y = cvtpk(c[2], c[3]);
        oa.z = cvtpk(c[4], c[5]);   oa.w = cvtpk(c[6], c[7]);
        ob.x = cvtpk(c[8], c[9]);   ob.y = cvtpk(c[10], c[11]);
        ob.z = cvtpk(c[12], c[13]); ob.w = cvtpk(c[14], c[15]);
        ushort* op = ctx + (size_t)pix * 256 + cbase;
        *(uint4*)op = oa;
        *(uint4*)(op + 8) = ob;
    }
}

// ------------- out GEMM (128x128, NCHW fp32 epilogue) -----------------------
__global__ __launch_bounds__(256, 2)
void gemm_out(const ushort* __restrict__ X, const ushort* __restrict__ Y,
              const float* __restrict__ bias, float* __restrict__ zf){
    __shared__ ushort ldsX[2][128 * 64];
    __shared__ ushort ldsY[2][128 * 64];
    const int tid  = threadIdx.x;
    const int lane = tid & 63;
    const int wid  = tid >> 6;
    const int wm   = wid >> 1, wn = wid & 1;
    const int x0   = blockIdx.x * 128, y0 = blockIdx.y * 128;

    auto stage = [&](int buf, int k0){
#pragma unroll
        for (int i = 0; i < 4; ++i){
            int f   = i * 256 + tid;
            int row = f >> 3, cp = f & 7;
            int cs  = cp ^ (row & 7);
            const ushort* gx = X + (size_t)(x0 + row) * KDIM + k0 + cs * 8;
            const ushort* gy = Y + (size_t)(y0 + row) * KDIM + k0 + cs * 8;
            __builtin_amdgcn_global_load_lds(
                (const __attribute__((address_space(1))) void*)gx,
                (__attribute__((address_space(3))) void*)&ldsX[buf][f * 8], 16, 0, 0);
            __builtin_amdgcn_global_load_lds(
                (const __attribute__((address_space(1))) void*)gy,
                (__attribute__((address_space(3))) void*)&ldsY[buf][f * 8], 16, 0, 0);
        }
    };

#pragma unroll 1
    for (int rep = 0; rep < REPS; ++rep){
        asm volatile("" ::: "memory");
        f32x4 acc[4][4];
#pragma unroll
        for (int i = 0; i < 4; ++i)
#pragma unroll
            for (int j = 0; j < 4; ++j) acc[i][j] = f32x4{0.f, 0.f, 0.f, 0.f};

        stage(0, 0);
        int buf = 0;
        for (int t = 0; t < 4; ++t){
            __syncthreads();
            if (t < 3) stage(buf ^ 1, (t + 1) * 64);
#pragma unroll
            for (int kk = 0; kk < 2; ++kk){
                bf16x8 xa[4], yb[4];
#pragma unroll
                for (int fm = 0; fm < 4; ++fm){
                    int r = wm * 64 + fm * 16 + (lane & 15);
                    int c = kk * 4 + (lane >> 4);
                    xa[fm] = *(const bf16x8*)&ldsX[buf][(r * 8 + (c ^ (r & 7))) * 8];
                }
#pragma unroll
                for (int fn = 0; fn < 4; ++fn){
                    int r = wn * 64 + fn * 16 + (lane & 15);
                    int c = kk * 4 + (lane >> 4);
                    yb[fn] = *(const bf16x8*)&ldsY[buf][(r * 8 + (c ^ (r & 7))) * 8];
                }
#pragma unroll
                for (int fm = 0; fm < 4; ++fm)
#pragma unroll
                    for (int fn = 0; fn < 4; ++fn)
                        acc[fm][fn] = __builtin_amdgcn_mfma_f32_16x16x32_bf16(
                            xa[fm], yb[fn], acc[fm][fn], 0, 0, 0);
            }
            buf ^= 1;
        }

#pragma unroll
        for (int fm = 0; fm < 4; ++fm){
#pragma unroll
            for (int fn = 0; fn < 4; ++fn){
                int xr = x0 + wm * 64 + fm * 16 + ((lane >> 4) << 2);
                int yc = y0 + wn * 64 + fn * 16 + (lane & 15);
                int bpix = yc >> 12, hw = yc & 4095;
#pragma unroll
                for (int r = 0; r < 4; ++r){
                    int ch = xr + r;
                    zf[((size_t)(bpix * 256 + ch)) * 4096 + hw] =
                        acc[fm][fn][r] + bias[ch];
                }
            }
        }
        __syncthreads();
    }
}

// ---------------------------------------------------------------------------
extern "C" void kernel_launch(void* const* d_in, const int* in_sizes, int n_in,
                              void* d_out, int out_size, void* d_ws, size_t ws_size,
                              hipStream_t stream){
    const float* x  = (const float*)d_in[0];
    const float* Wq = (const float*)d_in[1];
    const float* bq = (const float*)d_in[2];
    const float* Wk = (const float*)d_in[3];
    const float* bk = (const float*)d_in[4];
    const float* Wv = (const float*)d_in[5];
    const float* bv = (const float*)d_in[6];
    const float* Wo = (const float*)d_in[7];
    const float* bo = (const float*)d_in[8];
    float* out = (float*)d_out;

    char* ws = (char*)d_ws;
    ushort* wtq    = (ushort*)(ws);                // [4][768][256] bf16
    ushort* wot    = (ushort*)(ws + 1572864);      // [256][256] bf16
    float*  biasp  = (float*) (ws + 1703936);      // [4][768]
    float*  psum   = (float*) (ws + 1716224);      // [256][256]
    float*  psum2  = (float*) (ws + 1978368);      // [256][256]
    ushort* xt     = (ushort*)(ws + 2240512);      // [NPIX][256] bf16
    ushort* qkv    = (ushort*)(ws + 10629120);     // [NPIX+1][768] bf16 (+pad row)
    ushort* ctx    = (ushort*)(ws + 35796480);     // [NPIX][256] bf16

    ln_fuse<<<512, 256, 0, stream>>>(x, xt, psum, psum2);
    prep2<<<269, 256, 0, stream>>>(Wq, bq, Wk, bk, Wv, bv, Wo,
                                   psum, psum2, wtq, wot, biasp, qkv);

    gemm_qkv<<<256, 512, 0, stream>>>(xt, wtq, biasp, qkv);

    attn_win<<<1024, 256, 0, stream>>>(qkv, ctx);

    dim3 g2(2, 128);
    gemm_out<<<g2, 256, 0, stream>>>(wot, ctx, bo, out);
}

// Round 17
// 53.615 us; speedup vs baseline: 10.1228x; 10.1228x over previous
//
#include <hip/hip_runtime.h>
#include <hip/hip_bf16.h>
#include <stdint.h>

typedef __bf16 bf16x8 __attribute__((ext_vector_type(8)));
typedef float f32x4 __attribute__((ext_vector_type(4)));

#define KDIM 256
#define NPIX 16384       // 4*64*64 center pixels (no pad domain)
#define QKVS 768         // fused q/k/v row stride

__device__ __forceinline__ float b2f(ushort u){
    union { float f; uint32_t i; } x; x.i = ((uint32_t)u) << 16; return x.f;
}
__device__ __forceinline__ ushort f2b(float f){
    uint32_t u = __float_as_uint(f);
    uint32_t r = (u + 0x7fffu + ((u >> 16) & 1u)) >> 16;
    return (ushort)r;
}
__device__ __forceinline__ void unpack2(uint d, float& lo, float& hi){
    lo = __uint_as_float(d << 16);
    hi = __uint_as_float(d & 0xffff0000u);
}
__device__ __forceinline__ uint cvtpk(float lo, float hi){
    uint r;
    asm volatile("v_cvt_pk_bf16_f32 %0, %1, %2" : "=v"(r) : "v"(lo), "v"(hi));
    return r;
}

// --------- P1: single x pass -> bf16 CL transpose + fp32 LN partials --------
__global__ __launch_bounds__(256)
void ln_fuse(const float* __restrict__ x, ushort* __restrict__ xt,
             float* __restrict__ psum, float* __restrict__ psum2){
    __shared__ ushort sh[128 * 68];
    __shared__ float ssum[16 * 132], ssum2[16 * 132];
    const int bid = blockIdx.x;
    const int b = bid >> 7, rem = bid & 127, h = rem >> 1, ch = (rem & 1) * 128;
    const int tid = threadIdx.x;
    const int csub = tid >> 4, w4 = tid & 15;
#pragma unroll
    for (int i = 0; i < 8; ++i){
        int c = csub + 16 * i;            // local channel 0..127
        float4 v = *(const float4*)(x + ((size_t)(b * 256 + ch + c)) * 4096
                                      + h * 64 + w4 * 4);
        ushort4 u; u.x = f2b(v.x); u.y = f2b(v.y); u.z = f2b(v.z); u.w = f2b(v.w);
        *(ushort4*)&sh[c * 68 + w4 * 4] = u;
        ssum [w4 * 132 + c] = v.x + v.y + v.z + v.w;
        ssum2[w4 * 132 + c] = v.x * v.x + v.y * v.y + v.z * v.z + v.w * v.w;
    }
    __syncthreads();
    if (tid < 128){
        float S = 0.f, S2 = 0.f;
#pragma unroll
        for (int j = 0; j < 16; ++j){ S += ssum[j * 132 + tid]; S2 += ssum2[j * 132 + tid]; }
        psum [(b * 64 + h) * 256 + ch + tid] = S;
        psum2[(b * 64 + h) * 256 + ch + tid] = S2;
    }
    const int c16 = tid & 15, w16 = tid >> 4;
#pragma unroll
    for (int p = 0; p < 4; ++p){
        int w = p * 16 + w16;
        union { ushort u[8]; uint4 v; } r;
#pragma unroll
        for (int j = 0; j < 8; ++j) r.u[j] = sh[(c16 * 8 + j) * 68 + w];
        size_t row = (size_t)(b * 4096 + h * 64 + w);
        *(uint4*)(xt + row * 256 + ch + c16 * 8) = r.v;
    }
}

// --------- P2: per-b scaled weights + folded bias + pad row (block-range) ---
// Latency-path fixes vs R15: unrolled psum reduces (8-deep load ILP) and a
// wave-split float4 matvec for the folded bias (was 256 serial loads/thread).
__global__ __launch_bounds__(256)
void prep2(const float* __restrict__ Wq, const float* __restrict__ bq,
           const float* __restrict__ Wk, const float* __restrict__ bk,
           const float* __restrict__ Wv, const float* __restrict__ bv,
           const float* __restrict__ Wo,
           const float* __restrict__ psum, const float* __restrict__ psum2,
           ushort* __restrict__ wtq, ushort* __restrict__ wot,
           float* __restrict__ biasp, ushort* __restrict__ qkv){
    __shared__ float shW[32 * 33];
    __shared__ float shS[8 * 32], shS2[8 * 32], shRV[4 * 32], shM[256];
    __shared__ float shRed[4 * 256];
    const int bid = blockIdx.x, tid = threadIdx.x;
    if (bid < 192){
        int mat = bid / 64, tile = bid % 64;
        int ti = tile & 7, tj = tile >> 3;
        {
            int kk = tid & 31, idx = tid >> 5;        // idx: b*2 + h-half
            int b = idx >> 1, h0 = (idx & 1) * 32;
            float S = 0.f, S2 = 0.f;
#pragma unroll 8
            for (int r = 0; r < 32; ++r){
                int off = (b * 64 + h0 + r) * 256 + tj * 32 + kk;
                S += psum[off]; S2 += psum2[off];
            }
            shS[idx * 32 + kk] = S; shS2[idx * 32 + kk] = S2;
        }
        __syncthreads();
        if (tid < 128){
            int b = tid >> 5, kk = tid & 31;
            float S  = shS [(b * 2) * 32 + kk] + shS [(b * 2 + 1) * 32 + kk];
            float S2 = shS2[(b * 2) * 32 + kk] + shS2[(b * 2 + 1) * 32 + kk];
            float m = S * (1.f / 4096.f);
            float v = S2 * (1.f / 4096.f) - m * m;
            shRV[b * 32 + kk] = rsqrtf(v + 1e-5f);
        }
        const float* src = (mat == 0) ? Wq : (mat == 1) ? Wk : Wv;
        float qs = (mat == 0) ? 0.0625f : 1.0f;
        int tx = tid & 31, ty = tid >> 5;
#pragma unroll
        for (int i = 0; i < 4; ++i)
            shW[(ty + i * 8) * 33 + tx] =
                src[(size_t)(tj * 32 + ty + i * 8) * 256 + ti * 32 + tx] * qs;
        __syncthreads();
#pragma unroll
        for (int b = 0; b < 4; ++b){
            float rv = shRV[b * 32 + tx];
#pragma unroll
            for (int i = 0; i < 4; ++i){
                int n = mat * 256 + ti * 32 + ty + i * 8;
                wtq[((size_t)b * 768 + n) * 256 + tj * 32 + tx] =
                    f2b(shW[tx * 33 + ty + i * 8] * rv);
            }
        }
    } else if (bid < 256){
        int tile = bid - 192;
        int ti = tile & 7, tj = tile >> 3;
        int tx = tid & 31, ty = tid >> 5;
#pragma unroll
        for (int i = 0; i < 4; ++i)
            shW[(ty + i * 8) * 33 + tx] =
                Wo[(size_t)(tj * 32 + ty + i * 8) * 256 + ti * 32 + tx];
        __syncthreads();
#pragma unroll
        for (int i = 0; i < 4; ++i)
            wot[(size_t)(ti * 32 + ty + i * 8) * 256 + tj * 32 + tx] =
                f2b(shW[tx * 33 + ty + i * 8]);
    } else if (bid < 268){
        int t = bid - 256;
        int b = t / 3, mat = t % 3;
        // stats: thread tid handles channel c = tid, 8-deep load ILP
        float S = 0.f, S2 = 0.f;
#pragma unroll 8
        for (int h = 0; h < 64; ++h){
            S += psum[(b * 64 + h) * 256 + tid]; S2 += psum2[(b * 64 + h) * 256 + tid];
        }
        float m = S * (1.f / 4096.f);
        float v = S2 * (1.f / 4096.f) - m * m;
        shM[tid] = m * rsqrtf(v + 1e-5f);
        __syncthreads();
        // matvec: wave wv covers c in [wv*64, wv*64+64); lane owns 4 outputs
        const float* W  = (mat == 0) ? Wq : (mat == 1) ? Wk : Wv;
        const float* bb = (mat == 0) ? bq : (mat == 1) ? bk : bv;
        float qs = (mat == 0) ? 0.0625f : 1.0f;
        const int wv = tid >> 6, l = tid & 63;
        float4 a4 = {0.f, 0.f, 0.f, 0.f};
#pragma unroll 8
        for (int i = 0; i < 64; ++i){
            int c = wv * 64 + i;
            float4 w4 = *(const float4*)(W + (size_t)c * 256 + l * 4);
            float s = shM[c];
            a4.x += s * w4.x; a4.y += s * w4.y;
            a4.z += s * w4.z; a4.w += s * w4.w;
        }
        *(float4*)&shRed[wv * 256 + l * 4] = a4;
        __syncthreads();
        float acc = shRed[tid] + shRed[256 + tid] + shRed[512 + tid] + shRed[768 + tid];
        biasp[b * 768 + mat * 256 + tid] = (bb[tid] - acc) * qs;
    } else {
        // pad row at qkv[NPIX]: q part zero, k = bf16(bk), v = bf16(bv)
        ushort* pad = qkv + (size_t)NPIX * QKVS;
        pad[tid]       = 0;
        pad[256 + tid] = f2b(bk[tid]);
        pad[512 + tid] = f2b(bv[tid]);
    }
}

// ---- QKV GEMM: 256x192 tile, BK=64, 8 waves, counted vmcnt, 256 blocks ----
__global__ __launch_bounds__(512, 1)
void gemm_qkv(const ushort* __restrict__ X, const ushort* __restrict__ Y,
              const float* __restrict__ bias, ushort* __restrict__ zb){
    __shared__ ushort ldsA[2][256 * 64];   // 64 KB
    __shared__ ushort ldsB[2][192 * 64];   // 48 KB
    const int tid  = threadIdx.x;
    const int lane = tid & 63;
    const int wid  = tid >> 6;            // 0..7
    const int wm   = wid >> 2;            // 0..1 : rows wm*128
    const int wn   = wid & 3;             // 0..3 : cols wn*48
    const int tile  = (blockIdx.x & 7) * 32 + (blockIdx.x >> 3);  // XCD swizzle
    const int mtile = tile >> 2, ntile = tile & 3;                // ntile fastest
    const int x0 = mtile * 256, y0 = ntile * 192;
    const int bsel = x0 >> 12;
    const ushort* Yb   = Y + ((size_t)bsel * QKVS + y0) * 256;
    const float* biasb = bias + bsel * QKVS;

    auto stage = [&](int buf, int k0){
#pragma unroll
        for (int i = 0; i < 4; ++i){
            int f   = i * 512 + tid;          // A chunk 0..2047
            int row = f >> 3, cp = f & 7;
            int cs  = cp ^ (row & 7);
            const ushort* ga = X + (size_t)(x0 + row) * KDIM + k0 + cs * 8;
            __builtin_amdgcn_global_load_lds(
                (const __attribute__((address_space(1))) void*)ga,
                (__attribute__((address_space(3))) void*)&ldsA[buf][f * 8], 16, 0, 0);
        }
#pragma unroll
        for (int i = 0; i < 3; ++i){
            int f   = i * 512 + tid;          // B chunk 0..1535
            int row = f >> 3, cp = f & 7;
            int cs  = cp ^ (row & 7);
            const ushort* gb = Yb + (size_t)row * KDIM + k0 + cs * 8;
            __builtin_amdgcn_global_load_lds(
                (const __attribute__((address_space(1))) void*)gb,
                (__attribute__((address_space(3))) void*)&ldsB[buf][f * 8], 16, 0, 0);
        }
    };

    f32x4 acc[8][3];
#pragma unroll
    for (int i = 0; i < 8; ++i)
#pragma unroll
        for (int j = 0; j < 3; ++j) acc[i][j] = f32x4{0.f, 0.f, 0.f, 0.f};

    stage(0, 0);
    stage(1, 64);
#pragma unroll
    for (int t = 0; t < 4; ++t){
        if (t < 3) asm volatile("s_waitcnt vmcnt(7)" ::: "memory");
        else       asm volatile("s_waitcnt vmcnt(0)" ::: "memory");
        __builtin_amdgcn_sched_barrier(0);
        __builtin_amdgcn_s_barrier();
        __builtin_amdgcn_sched_barrier(0);
        const int buf = t & 1;
        __builtin_amdgcn_s_setprio(1);
#pragma unroll
        for (int kk = 0; kk < 2; ++kk){
            bf16x8 af[8], bf[3];
#pragma unroll
            for (int fm = 0; fm < 8; ++fm){
                int r = wm * 128 + fm * 16 + (lane & 15);
                int c = kk * 4 + (lane >> 4);
                af[fm] = *(const bf16x8*)&ldsA[buf][(r * 8 + (c ^ (r & 7))) * 8];
            }
#pragma unroll
            for (int fn = 0; fn < 3; ++fn){
                int r = wn * 48 + fn * 16 + (lane & 15);
                int c = kk * 4 + (lane >> 4);
                bf[fn] = *(const bf16x8*)&ldsB[buf][(r * 8 + (c ^ (r & 7))) * 8];
            }
#pragma unroll
            for (int fm = 0; fm < 8; ++fm)
#pragma unroll
                for (int fn = 0; fn < 3; ++fn)
                    acc[fm][fn] = __builtin_amdgcn_mfma_f32_16x16x32_bf16(
                        af[fm], bf[fn], acc[fm][fn], 0, 0, 0);
        }
        __builtin_amdgcn_s_setprio(0);
        __builtin_amdgcn_sched_barrier(0);
        __builtin_amdgcn_s_barrier();
        __builtin_amdgcn_sched_barrier(0);
        if (t < 2) stage(t & 1, (t + 2) * 64);
    }

#pragma unroll
    for (int fm = 0; fm < 8; ++fm){
#pragma unroll
        for (int fn = 0; fn < 3; ++fn){
            int xr = x0 + wm * 128 + fm * 16 + ((lane >> 4) << 2);
            int yc = y0 + wn * 48 + fn * 16 + (lane & 15);
            float bv = biasb[yc];
#pragma unroll
            for (int r = 0; r < 4; ++r)
                zb[(size_t)(xr + r) * QKVS + yc] = f2b(acc[fm][fn][r] + bv);
        }
    }
}

// --------- 3x3 window attention: 16 lanes/pixel, 4x4 tiles, XCD swizzle -----
__global__ __launch_bounds__(256)
void attn_win(const ushort* __restrict__ qkv, ushort* __restrict__ ctx){
    const int tid = threadIdx.x;
    const int lane = tid & 63, wid = tid >> 6;
    const int l16 = lane & 15, pg = lane >> 4;
    const int obid = (blockIdx.x & 7) * 128 + (blockIdx.x >> 3);  // XCD swizzle
    const int t = obid & 255, b = obid >> 8;
    const int tr = t >> 4, tc = t & 15;
    const int p = wid * 4 + pg;               // pixel 0..15 within tile
    const int h = tr * 4 + (p >> 2), w = tc * 4 + (p & 3);
    const int pix = (b << 12) + (h << 6) + w;
    const uint PADOFF = (uint)NPIX * QKVS;
    const int cbase = l16 * 16;

    const ushort* qp = qkv + (size_t)pix * QKVS + cbase;
    uint4 qa = *(const uint4*)qp;
    uint4 qb = *(const uint4*)(qp + 8);
    float qf[16];
    unpack2(qa.x, qf[0], qf[1]);  unpack2(qa.y, qf[2], qf[3]);
    unpack2(qa.z, qf[4], qf[5]);  unpack2(qa.w, qf[6], qf[7]);
    unpack2(qb.x, qf[8], qf[9]);  unpack2(qb.y, qf[10], qf[11]);
    unpack2(qb.z, qf[12], qf[13]); unpack2(qb.w, qf[14], qf[15]);

    float lg[9];
    uint roff[9];
#pragma unroll
    for (int n = 0; n < 9; ++n){
        int nh = h + n / 3 - 1, nw = w + n % 3 - 1;
        bool ok = ((unsigned)nh < 64u) & ((unsigned)nw < 64u);
        roff[n] = ok ? (uint)(((b << 12) + (nh << 6) + nw) * QKVS) : PADOFF;
        const ushort* kp = qkv + roff[n] + 256 + cbase;
        uint4 ka = *(const uint4*)kp;
        uint4 kb = *(const uint4*)(kp + 8);
        float kf[16];
        unpack2(ka.x, kf[0], kf[1]);  unpack2(ka.y, kf[2], kf[3]);
        unpack2(ka.z, kf[4], kf[5]);  unpack2(ka.w, kf[6], kf[7]);
        unpack2(kb.x, kf[8], kf[9]);  unpack2(kb.y, kf[10], kf[11]);
        unpack2(kb.z, kf[12], kf[13]); unpack2(kb.w, kf[14], kf[15]);
        float d = 0.f;
#pragma unroll
        for (int j = 0; j < 16; ++j) d += qf[j] * kf[j];
        d += __shfl_xor(d, 1); d += __shfl_xor(d, 2);
        d += __shfl_xor(d, 4); d += __shfl_xor(d, 8);
        lg[n] = d;
    }
    float m = lg[0];
#pragma unroll
    for (int n = 1; n < 9; ++n) m = fmaxf(m, lg[n]);
    float e[9], s = 0.f;
#pragma unroll
    for (int n = 0; n < 9; ++n){ e[n] = __expf(lg[n] - m); s += e[n]; }
    float inv = 1.f / s;

    float c[16];
#pragma unroll
    for (int j = 0; j < 16; ++j) c[j] = 0.f;
#pragma unroll
    for (int n = 0; n < 9; ++n){
        float a = e[n] * inv;
        const ushort* vp = qkv + roff[n] + 512 + cbase;
        uint4 va = *(const uint4*)vp;
        uint4 vb = *(const uint4*)(vp + 8);
        float vf[16];
        unpack2(va.x, vf[0], vf[1]);  unpack2(va.y, vf[2], vf[3]);
        unpack2(va.z, vf[4], vf[5]);  unpack2(va.w, vf[6], vf[7]);
        unpack2(vb.x, vf[8], vf[9]);  unpack2(vb.y, vf[10], vf[11]);
        unpack2(vb.z, vf[12], vf[13]); unpack2(vb.w, vf[14], vf[15]);
#pragma unroll
        for (int j = 0; j < 16; ++j) c[j] += a * vf[j];
    }
    uint4 oa, ob;
    oa.x = cvtpk(c[0], c[1]);   oa.y = cvtpk(c[2], c[3]);
    oa.z = cvtpk(c[4], c[5]);   oa.w = cvtpk(c[6], c[7]);
    ob.x = cvtpk(c[8], c[9]);   ob.y = cvtpk(c[10], c[11]);
    ob.z = cvtpk(c[12], c[13]); ob.w = cvtpk(c[14], c[15]);
    ushort* op = ctx + (size_t)pix * 256 + cbase;
    *(uint4*)op = oa;
    *(uint4*)(op + 8) = ob;
}

// ------------- out GEMM (128x128, NCHW fp32 epilogue) -----------------------
__global__ __launch_bounds__(256, 2)
void gemm_out(const ushort* __restrict__ X, const ushort* __restrict__ Y,
              const float* __restrict__ bias, float* __restrict__ zf){
    __shared__ ushort ldsX[2][128 * 64];
    __shared__ ushort ldsY[2][128 * 64];
    const int tid  = threadIdx.x;
    const int lane = tid & 63;
    const int wid  = tid >> 6;
    const int wm   = wid >> 1, wn = wid & 1;
    const int x0   = blockIdx.x * 128, y0 = blockIdx.y * 128;

    auto stage = [&](int buf, int k0){
#pragma unroll
        for (int i = 0; i < 4; ++i){
            int f   = i * 256 + tid;
            int row = f >> 3, cp = f & 7;
            int cs  = cp ^ (row & 7);
            const ushort* gx = X + (size_t)(x0 + row) * KDIM + k0 + cs * 8;
            const ushort* gy = Y + (size_t)(y0 + row) * KDIM + k0 + cs * 8;
            __builtin_amdgcn_global_load_lds(
                (const __attribute__((address_space(1))) void*)gx,
                (__attribute__((address_space(3))) void*)&ldsX[buf][f * 8], 16, 0, 0);
            __builtin_amdgcn_global_load_lds(
                (const __attribute__((address_space(1))) void*)gy,
                (__attribute__((address_space(3))) void*)&ldsY[buf][f * 8], 16, 0, 0);
        }
    };

    f32x4 acc[4][4];
#pragma unroll
    for (int i = 0; i < 4; ++i)
#pragma unroll
        for (int j = 0; j < 4; ++j) acc[i][j] = f32x4{0.f, 0.f, 0.f, 0.f};

    stage(0, 0);
    int buf = 0;
    for (int t = 0; t < 4; ++t){
        __syncthreads();
        if (t < 3) stage(buf ^ 1, (t + 1) * 64);
#pragma unroll
        for (int kk = 0; kk < 2; ++kk){
            bf16x8 xa[4], yb[4];
#pragma unroll
            for (int fm = 0; fm < 4; ++fm){
                int r = wm * 64 + fm * 16 + (lane & 15);
                int c = kk * 4 + (lane >> 4);
                xa[fm] = *(const bf16x8*)&ldsX[buf][(r * 8 + (c ^ (r & 7))) * 8];
            }
#pragma unroll
            for (int fn = 0; fn < 4; ++fn){
                int r = wn * 64 + fn * 16 + (lane & 15);
                int c = kk * 4 + (lane >> 4);
                yb[fn] = *(const bf16x8*)&ldsY[buf][(r * 8 + (c ^ (r & 7))) * 8];
            }
#pragma unroll
            for (int fm = 0; fm < 4; ++fm)
#pragma unroll
                for (int fn = 0; fn < 4; ++fn)
                    acc[fm][fn] = __builtin_amdgcn_mfma_f32_16x16x32_bf16(
                        xa[fm], yb[fn], acc[fm][fn], 0, 0, 0);
        }
        buf ^= 1;
    }

#pragma unroll
    for (int fm = 0; fm < 4; ++fm){
#pragma unroll
        for (int fn = 0; fn < 4; ++fn){
            int xr = x0 + wm * 64 + fm * 16 + ((lane >> 4) << 2);
            int yc = y0 + wn * 64 + fn * 16 + (lane & 15);
            int bpix = yc >> 12, hw = yc & 4095;
#pragma unroll
            for (int r = 0; r < 4; ++r){
                int ch = xr + r;
                zf[((size_t)(bpix * 256 + ch)) * 4096 + hw] =
                    acc[fm][fn][r] + bias[ch];
            }
        }
    }
}

// ---------------------------------------------------------------------------
extern "C" void kernel_launch(void* const* d_in, const int* in_sizes, int n_in,
                              void* d_out, int out_size, void* d_ws, size_t ws_size,
                              hipStream_t stream){
    const float* x  = (const float*)d_in[0];
    const float* Wq = (const float*)d_in[1];
    const float* bq = (const float*)d_in[2];
    const float* Wk = (const float*)d_in[3];
    const float* bk = (const float*)d_in[4];
    const float* Wv = (const float*)d_in[5];
    const float* bv = (const float*)d_in[6];
    const float* Wo = (const float*)d_in[7];
    const float* bo = (const float*)d_in[8];
    float* out = (float*)d_out;

    char* ws = (char*)d_ws;
    ushort* wtq    = (ushort*)(ws);                // [4][768][256] bf16
    ushort* wot    = (ushort*)(ws + 1572864);      // [256][256] bf16
    float*  biasp  = (float*) (ws + 1703936);      // [4][768]
    float*  psum   = (float*) (ws + 1716224);      // [256][256]
    float*  psum2  = (float*) (ws + 1978368);      // [256][256]
    ushort* xt     = (ushort*)(ws + 2240512);      // [NPIX][256] bf16
    ushort* qkv    = (ushort*)(ws + 10629120);     // [NPIX+1][768] bf16 (+pad row)
    ushort* ctx    = (ushort*)(ws + 35796480);     // [NPIX][256] bf16

    ln_fuse<<<512, 256, 0, stream>>>(x, xt, psum, psum2);
    prep2<<<269, 256, 0, stream>>>(Wq, bq, Wk, bk, Wv, bv, Wo,
                                   psum, psum2, wtq, wot, biasp, qkv);

    gemm_qkv<<<256, 512, 0, stream>>>(xt, wtq, biasp, qkv);   // 64 M x 4 N tiles

    attn_win<<<1024, 256, 0, stream>>>(qkv, ctx);

    dim3 g2(2, 128);
    gemm_out<<<g2, 256, 0, stream>>>(wot, ctx, bo, out);
}

// Round 18
// 52.327 us; speedup vs baseline: 10.3719x; 1.0246x over previous
//
#include <hip/hip_runtime.h>
#include <hip/hip_bf16.h>
#include <stdint.h>

typedef __bf16 bf16x8 __attribute__((ext_vector_type(8)));
typedef float f32x4 __attribute__((ext_vector_type(4)));

#define KDIM 256
#define NPIX 16384       // 4*64*64 center pixels (no pad domain)
#define QKVS 768         // fused q/k/v row stride

__device__ __forceinline__ float b2f(ushort u){
    union { float f; uint32_t i; } x; x.i = ((uint32_t)u) << 16; return x.f;
}
__device__ __forceinline__ ushort f2b(float f){
    uint32_t u = __float_as_uint(f);
    uint32_t r = (u + 0x7fffu + ((u >> 16) & 1u)) >> 16;
    return (ushort)r;
}
__device__ __forceinline__ void unpack2(uint d, float& lo, float& hi){
    lo = __uint_as_float(d << 16);
    hi = __uint_as_float(d & 0xffff0000u);
}
__device__ __forceinline__ uint cvtpk(float lo, float hi){
    uint r;
    asm volatile("v_cvt_pk_bf16_f32 %0, %1, %2" : "=v"(r) : "v"(lo), "v"(hi));
    return r;
}

// --------- P1: single x pass -> bf16 CL transpose + fp32 LN partials --------
__global__ __launch_bounds__(256)
void ln_fuse(const float* __restrict__ x, ushort* __restrict__ xt,
             float* __restrict__ psum, float* __restrict__ psum2){
    __shared__ ushort sh[128 * 68];
    __shared__ float ssum[16 * 132], ssum2[16 * 132];
    const int bid = blockIdx.x;
    const int b = bid >> 7, rem = bid & 127, h = rem >> 1, ch = (rem & 1) * 128;
    const int tid = threadIdx.x;
    const int csub = tid >> 4, w4 = tid & 15;
#pragma unroll
    for (int i = 0; i < 8; ++i){
        int c = csub + 16 * i;            // local channel 0..127
        float4 v = *(const float4*)(x + ((size_t)(b * 256 + ch + c)) * 4096
                                      + h * 64 + w4 * 4);
        ushort4 u; u.x = f2b(v.x); u.y = f2b(v.y); u.z = f2b(v.z); u.w = f2b(v.w);
        *(ushort4*)&sh[c * 68 + w4 * 4] = u;
        ssum [w4 * 132 + c] = v.x + v.y + v.z + v.w;
        ssum2[w4 * 132 + c] = v.x * v.x + v.y * v.y + v.z * v.z + v.w * v.w;
    }
    __syncthreads();
    if (tid < 128){
        float S = 0.f, S2 = 0.f;
#pragma unroll
        for (int j = 0; j < 16; ++j){ S += ssum[j * 132 + tid]; S2 += ssum2[j * 132 + tid]; }
        psum [(b * 64 + h) * 256 + ch + tid] = S;
        psum2[(b * 64 + h) * 256 + ch + tid] = S2;
    }
    const int c16 = tid & 15, w16 = tid >> 4;
#pragma unroll
    for (int p = 0; p < 4; ++p){
        int w = p * 16 + w16;
        union { ushort u[8]; uint4 v; } r;
#pragma unroll
        for (int j = 0; j < 8; ++j) r.u[j] = sh[(c16 * 8 + j) * 68 + w];
        size_t row = (size_t)(b * 4096 + h * 64 + w);
        *(uint4*)(xt + row * 256 + ch + c16 * 8) = r.v;
    }
}

// --------- P2: per-b scaled weights + folded bias + pad row (block-range) ---
__global__ __launch_bounds__(256)
void prep2(const float* __restrict__ Wq, const float* __restrict__ bq,
           const float* __restrict__ Wk, const float* __restrict__ bk,
           const float* __restrict__ Wv, const float* __restrict__ bv,
           const float* __restrict__ Wo,
           const float* __restrict__ psum, const float* __restrict__ psum2,
           ushort* __restrict__ wtq, ushort* __restrict__ wot,
           float* __restrict__ biasp, ushort* __restrict__ qkv){
    __shared__ float shW[32 * 33];
    __shared__ float shS[8 * 32], shS2[8 * 32], shRV[4 * 32], shM[256];
    __shared__ float shRed[4 * 256];
    const int bid = blockIdx.x, tid = threadIdx.x;
    if (bid < 192){
        int mat = bid / 64, tile = bid % 64;
        int ti = tile & 7, tj = tile >> 3;
        // hoist independent W loads so their latency overlaps the stats reduce
        const float* src = (mat == 0) ? Wq : (mat == 1) ? Wk : Wv;
        float qs = (mat == 0) ? 0.0625f : 1.0f;
        int tx = tid & 31, ty = tid >> 5;
        float wreg[4];
#pragma unroll
        for (int i = 0; i < 4; ++i)
            wreg[i] = src[(size_t)(tj * 32 + ty + i * 8) * 256 + ti * 32 + tx] * qs;
        {
            int kk = tid & 31, idx = tid >> 5;        // idx: b*2 + h-half
            int b = idx >> 1, h0 = (idx & 1) * 32;
            float S = 0.f, S2 = 0.f;
#pragma unroll 8
            for (int r = 0; r < 32; ++r){
                int off = (b * 64 + h0 + r) * 256 + tj * 32 + kk;
                S += psum[off]; S2 += psum2[off];
            }
            shS[idx * 32 + kk] = S; shS2[idx * 32 + kk] = S2;
        }
        __syncthreads();
        if (tid < 128){
            int b = tid >> 5, kk = tid & 31;
            float S  = shS [(b * 2) * 32 + kk] + shS [(b * 2 + 1) * 32 + kk];
            float S2 = shS2[(b * 2) * 32 + kk] + shS2[(b * 2 + 1) * 32 + kk];
            float m = S * (1.f / 4096.f);
            float v = S2 * (1.f / 4096.f) - m * m;
            shRV[b * 32 + kk] = rsqrtf(v + 1e-5f);
        }
#pragma unroll
        for (int i = 0; i < 4; ++i)
            shW[(ty + i * 8) * 33 + tx] = wreg[i];
        __syncthreads();
#pragma unroll
        for (int b = 0; b < 4; ++b){
            float rv = shRV[b * 32 + tx];
#pragma unroll
            for (int i = 0; i < 4; ++i){
                int n = mat * 256 + ti * 32 + ty + i * 8;
                wtq[((size_t)b * 768 + n) * 256 + tj * 32 + tx] =
                    f2b(shW[tx * 33 + ty + i * 8] * rv);
            }
        }
    } else if (bid < 256){
        int tile = bid - 192;
        int ti = tile & 7, tj = tile >> 3;
        int tx = tid & 31, ty = tid >> 5;
#pragma unroll
        for (int i = 0; i < 4; ++i)
            shW[(ty + i * 8) * 33 + tx] =
                Wo[(size_t)(tj * 32 + ty + i * 8) * 256 + ti * 32 + tx];
        __syncthreads();
#pragma unroll
        for (int i = 0; i < 4; ++i)
            wot[(size_t)(ti * 32 + ty + i * 8) * 256 + tj * 32 + tx] =
                f2b(shW[tx * 33 + ty + i * 8]);
    } else if (bid < 268){
        int t = bid - 256;
        int b = t / 3, mat = t % 3;
        float S = 0.f, S2 = 0.f;
#pragma unroll 8
        for (int h = 0; h < 64; ++h){
            S += psum[(b * 64 + h) * 256 + tid]; S2 += psum2[(b * 64 + h) * 256 + tid];
        }
        float m = S * (1.f / 4096.f);
        float v = S2 * (1.f / 4096.f) - m * m;
        shM[tid] = m * rsqrtf(v + 1e-5f);
        __syncthreads();
        const float* W  = (mat == 0) ? Wq : (mat == 1) ? Wk : Wv;
        const float* bb = (mat == 0) ? bq : (mat == 1) ? bk : bv;
        float qs = (mat == 0) ? 0.0625f : 1.0f;
        const int wv = tid >> 6, l = tid & 63;
        float4 a4 = {0.f, 0.f, 0.f, 0.f};
#pragma unroll 8
        for (int i = 0; i < 64; ++i){
            int c = wv * 64 + i;
            float4 w4 = *(const float4*)(W + (size_t)c * 256 + l * 4);
            float s = shM[c];
            a4.x += s * w4.x; a4.y += s * w4.y;
            a4.z += s * w4.z; a4.w += s * w4.w;
        }
        *(float4*)&shRed[wv * 256 + l * 4] = a4;
        __syncthreads();
        float acc = shRed[tid] + shRed[256 + tid] + shRed[512 + tid] + shRed[768 + tid];
        biasp[b * 768 + mat * 256 + tid] = (bb[tid] - acc) * qs;
    } else {
        // pad row at qkv[NPIX]: q part zero, k = bf16(bk), v = bf16(bv)
        ushort* pad = qkv + (size_t)NPIX * QKVS;
        pad[tid]       = 0;
        pad[256 + tid] = f2b(bk[tid]);
        pad[512 + tid] = f2b(bv[tid]);
    }
}

// ---- QKV GEMM: 128x192 tile, BK=64, 8 waves, counted vmcnt, 512 blocks -----
// 80 KB LDS -> 2 blocks/CU (cross-block TLP hides barrier/vmcnt stalls).
// XCD swizzle: each XCD owns 16 m-tiles x 4 n-tiles (A-panel L2 reuse).
__global__ __launch_bounds__(512, 4)
void gemm_qkv(const ushort* __restrict__ X, const ushort* __restrict__ Y,
              const float* __restrict__ bias, ushort* __restrict__ zb){
    __shared__ ushort ldsA[2][128 * 64];   // 32 KB
    __shared__ ushort ldsB[2][192 * 64];   // 48 KB
    const int tid  = threadIdx.x;
    const int lane = tid & 63;
    const int wid  = tid >> 6;            // 0..7
    const int wm   = wid >> 2;            // 0..1 : rows wm*64
    const int wn   = wid & 3;             // 0..3 : cols wn*48
    const int tile  = (blockIdx.x & 7) * 64 + (blockIdx.x >> 3);  // XCD swizzle
    const int mtile = tile >> 2, ntile = tile & 3;                // ntile fastest
    const int x0 = mtile * 128, y0 = ntile * 192;
    const int bsel = x0 >> 12;
    const ushort* Yb   = Y + ((size_t)bsel * QKVS + y0) * 256;
    const float* biasb = bias + bsel * QKVS;

    // T2 chunk swizzle; 5 loads/thread per stage (2 A + 3 B), wave-uniform.
    auto stage = [&](int buf, int k0){
#pragma unroll
        for (int i = 0; i < 2; ++i){
            int f   = i * 512 + tid;          // A chunk 0..1023
            int row = f >> 3, cp = f & 7;
            int cs  = cp ^ (row & 7);
            const ushort* ga = X + (size_t)(x0 + row) * KDIM + k0 + cs * 8;
            __builtin_amdgcn_global_load_lds(
                (const __attribute__((address_space(1))) void*)ga,
                (__attribute__((address_space(3))) void*)&ldsA[buf][f * 8], 16, 0, 0);
        }
#pragma unroll
        for (int i = 0; i < 3; ++i){
            int f   = i * 512 + tid;          // B chunk 0..1535
            int row = f >> 3, cp = f & 7;
            int cs  = cp ^ (row & 7);
            const ushort* gb = Yb + (size_t)row * KDIM + k0 + cs * 8;
            __builtin_amdgcn_global_load_lds(
                (const __attribute__((address_space(1))) void*)gb,
                (__attribute__((address_space(3))) void*)&ldsB[buf][f * 8], 16, 0, 0);
        }
    };

    f32x4 acc[4][3];
#pragma unroll
    for (int i = 0; i < 4; ++i)
#pragma unroll
        for (int j = 0; j < 3; ++j) acc[i][j] = f32x4{0.f, 0.f, 0.f, 0.f};

    stage(0, 0);
    stage(1, 64);
#pragma unroll
    for (int t = 0; t < 4; ++t){
        // wait for K-tile t only (5 loads/thread of tile t+1 may stay in flight)
        if (t < 3) asm volatile("s_waitcnt vmcnt(5)" ::: "memory");
        else       asm volatile("s_waitcnt vmcnt(0)" ::: "memory");
        __builtin_amdgcn_sched_barrier(0);
        __builtin_amdgcn_s_barrier();
        __builtin_amdgcn_sched_barrier(0);
        const int buf = t & 1;
        __builtin_amdgcn_s_setprio(1);
#pragma unroll
        for (int kk = 0; kk < 2; ++kk){
            bf16x8 af[4], bf[3];
#pragma unroll
            for (int fm = 0; fm < 4; ++fm){
                int r = wm * 64 + fm * 16 + (lane & 15);
                int c = kk * 4 + (lane >> 4);
                af[fm] = *(const bf16x8*)&ldsA[buf][(r * 8 + (c ^ (r & 7))) * 8];
            }
#pragma unroll
            for (int fn = 0; fn < 3; ++fn){
                int r = wn * 48 + fn * 16 + (lane & 15);
                int c = kk * 4 + (lane >> 4);
                bf[fn] = *(const bf16x8*)&ldsB[buf][(r * 8 + (c ^ (r & 7))) * 8];
            }
#pragma unroll
            for (int fm = 0; fm < 4; ++fm)
#pragma unroll
                for (int fn = 0; fn < 3; ++fn)
                    acc[fm][fn] = __builtin_amdgcn_mfma_f32_16x16x32_bf16(
                        af[fm], bf[fn], acc[fm][fn], 0, 0, 0);
        }
        __builtin_amdgcn_s_setprio(0);
        __builtin_amdgcn_sched_barrier(0);
        __builtin_amdgcn_s_barrier();
        __builtin_amdgcn_sched_barrier(0);
        if (t < 2) stage(t & 1, (t + 2) * 64);
    }

    // epilogue: col = lane&15 (B-row), row = (lane>>4)*4 + r (A-row)
#pragma unroll
    for (int fm = 0; fm < 4; ++fm){
#pragma unroll
        for (int fn = 0; fn < 3; ++fn){
            int xr = x0 + wm * 64 + fm * 16 + ((lane >> 4) << 2);
            int yc = y0 + wn * 48 + fn * 16 + (lane & 15);
            float bv = biasb[yc];
#pragma unroll
            for (int r = 0; r < 4; ++r)
                zb[(size_t)(xr + r) * QKVS + yc] = f2b(acc[fm][fn][r] + bv);
        }
    }
}

// --------- 3x3 window attention: 16 lanes/pixel, 4x4 tiles, XCD swizzle -----
__global__ __launch_bounds__(256)
void attn_win(const ushort* __restrict__ qkv, ushort* __restrict__ ctx){
    const int tid = threadIdx.x;
    const int lane = tid & 63, wid = tid >> 6;
    const int l16 = lane & 15, pg = lane >> 4;
    const int obid = (blockIdx.x & 7) * 128 + (blockIdx.x >> 3);  // XCD swizzle
    const int t = obid & 255, b = obid >> 8;
    const int tr = t >> 4, tc = t & 15;
    const int p = wid * 4 + pg;               // pixel 0..15 within tile
    const int h = tr * 4 + (p >> 2), w = tc * 4 + (p & 3);
    const int pix = (b << 12) + (h << 6) + w;
    const uint PADOFF = (uint)NPIX * QKVS;
    const int cbase = l16 * 16;

    const ushort* qp = qkv + (size_t)pix * QKVS + cbase;
    uint4 qa = *(const uint4*)qp;
    uint4 qb = *(const uint4*)(qp + 8);
    float qf[16];
    unpack2(qa.x, qf[0], qf[1]);  unpack2(qa.y, qf[2], qf[3]);
    unpack2(qa.z, qf[4], qf[5]);  unpack2(qa.w, qf[6], qf[7]);
    unpack2(qb.x, qf[8], qf[9]);  unpack2(qb.y, qf[10], qf[11]);
    unpack2(qb.z, qf[12], qf[13]); unpack2(qb.w, qf[14], qf[15]);

    float lg[9];
    uint roff[9];
#pragma unroll
    for (int n = 0; n < 9; ++n){
        int nh = h + n / 3 - 1, nw = w + n % 3 - 1;
        bool ok = ((unsigned)nh < 64u) & ((unsigned)nw < 64u);
        roff[n] = ok ? (uint)(((b << 12) + (nh << 6) + nw) * QKVS) : PADOFF;
        const ushort* kp = qkv + roff[n] + 256 + cbase;
        uint4 ka = *(const uint4*)kp;
        uint4 kb = *(const uint4*)(kp + 8);
        float kf[16];
        unpack2(ka.x, kf[0], kf[1]);  unpack2(ka.y, kf[2], kf[3]);
        unpack2(ka.z, kf[4], kf[5]);  unpack2(ka.w, kf[6], kf[7]);
        unpack2(kb.x, kf[8], kf[9]);  unpack2(kb.y, kf[10], kf[11]);
        unpack2(kb.z, kf[12], kf[13]); unpack2(kb.w, kf[14], kf[15]);
        float d = 0.f;
#pragma unroll
        for (int j = 0; j < 16; ++j) d += qf[j] * kf[j];
        d += __shfl_xor(d, 1); d += __shfl_xor(d, 2);
        d += __shfl_xor(d, 4); d += __shfl_xor(d, 8);
        lg[n] = d;
    }
    float m = lg[0];
#pragma unroll
    for (int n = 1; n < 9; ++n) m = fmaxf(m, lg[n]);
    float e[9], s = 0.f;
#pragma unroll
    for (int n = 0; n < 9; ++n){ e[n] = __expf(lg[n] - m); s += e[n]; }
    float inv = 1.f / s;

    float c[16];
#pragma unroll
    for (int j = 0; j < 16; ++j) c[j] = 0.f;
#pragma unroll
    for (int n = 0; n < 9; ++n){
        float a = e[n] * inv;
        const ushort* vp = qkv + roff[n] + 512 + cbase;
        uint4 va = *(const uint4*)vp;
        uint4 vb = *(const uint4*)(vp + 8);
        float vf[16];
        unpack2(va.x, vf[0], vf[1]);  unpack2(va.y, vf[2], vf[3]);
        unpack2(va.z, vf[4], vf[5]);  unpack2(va.w, vf[6], vf[7]);
        unpack2(vb.x, vf[8], vf[9]);  unpack2(vb.y, vf[10], vf[11]);
        unpack2(vb.z, vf[12], vf[13]); unpack2(vb.w, vf[14], vf[15]);
#pragma unroll
        for (int j = 0; j < 16; ++j) c[j] += a * vf[j];
    }
    uint4 oa, ob;
    oa.x = cvtpk(c[0], c[1]);   oa.y = cvtpk(c[2], c[3]);
    oa.z = cvtpk(c[4], c[5]);   oa.w = cvtpk(c[6], c[7]);
    ob.x = cvtpk(c[8], c[9]);   ob.y = cvtpk(c[10], c[11]);
    ob.z = cvtpk(c[12], c[13]); ob.w = cvtpk(c[14], c[15]);
    ushort* op = ctx + (size_t)pix * 256 + cbase;
    *(uint4*)op = oa;
    *(uint4*)(op + 8) = ob;
}

// ------------- out GEMM (128x128, NCHW fp32 epilogue, XCD pair swizzle) -----
__global__ __launch_bounds__(256, 2)
void gemm_out(const ushort* __restrict__ X, const ushort* __restrict__ Y,
              const float* __restrict__ bias, float* __restrict__ zf){
    __shared__ ushort ldsX[2][128 * 64];
    __shared__ ushort ldsY[2][128 * 64];
    const int tid  = threadIdx.x;
    const int lane = tid & 63;
    const int wid  = tid >> 6;
    const int wm   = wid >> 1, wn = wid & 1;
    // 256 blocks: each XCD gets 32 tiles; ch-tile fastest -> ctx-panel pairs
    const int tile = (blockIdx.x & 7) * 32 + (blockIdx.x >> 3);
    const int x0   = (tile & 1) * 128;    // ch tile (2)
    const int y0   = (tile >> 1) * 128;   // pixel tile (128)

    auto stage = [&](int buf, int k0){
#pragma unroll
        for (int i = 0; i < 4; ++i){
            int f   = i * 256 + tid;
            int row = f >> 3, cp = f & 7;
            int cs  = cp ^ (row & 7);
            const ushort* gx = X + (size_t)(x0 + row) * KDIM + k0 + cs * 8;
            const ushort* gy = Y + (size_t)(y0 + row) * KDIM + k0 + cs * 8;
            __builtin_amdgcn_global_load_lds(
                (const __attribute__((address_space(1))) void*)gx,
                (__attribute__((address_space(3))) void*)&ldsX[buf][f * 8], 16, 0, 0);
            __builtin_amdgcn_global_load_lds(
                (const __attribute__((address_space(1))) void*)gy,
                (__attribute__((address_space(3))) void*)&ldsY[buf][f * 8], 16, 0, 0);
        }
    };

    f32x4 acc[4][4];
#pragma unroll
    for (int i = 0; i < 4; ++i)
#pragma unroll
        for (int j = 0; j < 4; ++j) acc[i][j] = f32x4{0.f, 0.f, 0.f, 0.f};

    stage(0, 0);
    int buf = 0;
    for (int t = 0; t < 4; ++t){
        __syncthreads();
        if (t < 3) stage(buf ^ 1, (t + 1) * 64);
#pragma unroll
        for (int kk = 0; kk < 2; ++kk){
            bf16x8 xa[4], yb[4];
#pragma unroll
            for (int fm = 0; fm < 4; ++fm){
                int r = wm * 64 + fm * 16 + (lane & 15);
                int c = kk * 4 + (lane >> 4);
                xa[fm] = *(const bf16x8*)&ldsX[buf][(r * 8 + (c ^ (r & 7))) * 8];
            }
#pragma unroll
            for (int fn = 0; fn < 4; ++fn){
                int r = wn * 64 + fn * 16 + (lane & 15);
                int c = kk * 4 + (lane >> 4);
                yb[fn] = *(const bf16x8*)&ldsY[buf][(r * 8 + (c ^ (r & 7))) * 8];
            }
#pragma unroll
            for (int fm = 0; fm < 4; ++fm)
#pragma unroll
                for (int fn = 0; fn < 4; ++fn)
                    acc[fm][fn] = __builtin_amdgcn_mfma_f32_16x16x32_bf16(
                        xa[fm], yb[fn], acc[fm][fn], 0, 0, 0);
        }
        buf ^= 1;
    }

#pragma unroll
    for (int fm = 0; fm < 4; ++fm){
#pragma unroll
        for (int fn = 0; fn < 4; ++fn){
            int xr = x0 + wm * 64 + fm * 16 + ((lane >> 4) << 2);
            int yc = y0 + wn * 64 + fn * 16 + (lane & 15);
            int bpix = yc >> 12, hw = yc & 4095;
#pragma unroll
            for (int r = 0; r < 4; ++r){
                int ch = xr + r;
                zf[((size_t)(bpix * 256 + ch)) * 4096 + hw] =
                    acc[fm][fn][r] + bias[ch];
            }
        }
    }
}

// ---------------------------------------------------------------------------
extern "C" void kernel_launch(void* const* d_in, const int* in_sizes, int n_in,
                              void* d_out, int out_size, void* d_ws, size_t ws_size,
                              hipStream_t stream){
    const float* x  = (const float*)d_in[0];
    const float* Wq = (const float*)d_in[1];
    const float* bq = (const float*)d_in[2];
    const float* Wk = (const float*)d_in[3];
    const float* bk = (const float*)d_in[4];
    const float* Wv = (const float*)d_in[5];
    const float* bv = (const float*)d_in[6];
    const float* Wo = (const float*)d_in[7];
    const float* bo = (const float*)d_in[8];
    float* out = (float*)d_out;

    char* ws = (char*)d_ws;
    ushort* wtq    = (ushort*)(ws);                // [4][768][256] bf16
    ushort* wot    = (ushort*)(ws + 1572864);      // [256][256] bf16
    float*  biasp  = (float*) (ws + 1703936);      // [4][768]
    float*  psum   = (float*) (ws + 1716224);      // [256][256]
    float*  psum2  = (float*) (ws + 1978368);      // [256][256]
    ushort* xt     = (ushort*)(ws + 2240512);      // [NPIX][256] bf16
    ushort* qkv    = (ushort*)(ws + 10629120);     // [NPIX+1][768] bf16 (+pad row)
    ushort* ctx    = (ushort*)(ws + 35796480);     // [NPIX][256] bf16

    ln_fuse<<<512, 256, 0, stream>>>(x, xt, psum, psum2);
    prep2<<<269, 256, 0, stream>>>(Wq, bq, Wk, bk, Wv, bv, Wo,
                                   psum, psum2, wtq, wot, biasp, qkv);

    gemm_qkv<<<512, 512, 0, stream>>>(xt, wtq, biasp, qkv);   // 128 M x 4 N tiles

    attn_win<<<1024, 256, 0, stream>>>(qkv, ctx);

    gemm_out<<<256, 256, 0, stream>>>(wot, ctx, bo, out);
}

// Round 19
// 50.251 us; speedup vs baseline: 10.8003x; 1.0413x over previous
//
#include <hip/hip_runtime.h>
#include <hip/hip_bf16.h>
#include <stdint.h>

typedef __bf16 bf16x8 __attribute__((ext_vector_type(8)));
typedef float f32x4 __attribute__((ext_vector_type(4)));

#define KDIM 256
#define NPIX 16384       // 4*64*64 center pixels (no pad domain)
#define QKVS 768         // fused q/k/v row stride
#define KVROW 520        // LDS row stride (512 + 8 pad: bank shift 4/row)

__device__ __forceinline__ float b2f(ushort u){
    union { float f; uint32_t i; } x; x.i = ((uint32_t)u) << 16; return x.f;
}
__device__ __forceinline__ ushort f2b(float f){
    uint32_t u = __float_as_uint(f);
    uint32_t r = (u + 0x7fffu + ((u >> 16) & 1u)) >> 16;
    return (ushort)r;
}
__device__ __forceinline__ void unpack2(uint d, float& lo, float& hi){
    lo = __uint_as_float(d << 16);
    hi = __uint_as_float(d & 0xffff0000u);
}
__device__ __forceinline__ uint cvtpk(float lo, float hi){
    uint r;
    asm volatile("v_cvt_pk_bf16_f32 %0, %1, %2" : "=v"(r) : "v"(lo), "v"(hi));
    return r;
}

// --------- P1: single x pass -> bf16 CL transpose + fp32 LN partials --------
__global__ __launch_bounds__(256)
void ln_fuse(const float* __restrict__ x, ushort* __restrict__ xt,
             float* __restrict__ psum, float* __restrict__ psum2){
    __shared__ ushort sh[128 * 68];
    __shared__ float ssum[16 * 132], ssum2[16 * 132];
    const int bid = blockIdx.x;
    const int b = bid >> 7, rem = bid & 127, h = rem >> 1, ch = (rem & 1) * 128;
    const int tid = threadIdx.x;
    const int csub = tid >> 4, w4 = tid & 15;
#pragma unroll
    for (int i = 0; i < 8; ++i){
        int c = csub + 16 * i;            // local channel 0..127
        float4 v = *(const float4*)(x + ((size_t)(b * 256 + ch + c)) * 4096
                                      + h * 64 + w4 * 4);
        ushort4 u; u.x = f2b(v.x); u.y = f2b(v.y); u.z = f2b(v.z); u.w = f2b(v.w);
        *(ushort4*)&sh[c * 68 + w4 * 4] = u;
        ssum [w4 * 132 + c] = v.x + v.y + v.z + v.w;
        ssum2[w4 * 132 + c] = v.x * v.x + v.y * v.y + v.z * v.z + v.w * v.w;
    }
    __syncthreads();
    if (tid < 128){
        float S = 0.f, S2 = 0.f;
#pragma unroll
        for (int j = 0; j < 16; ++j){ S += ssum[j * 132 + tid]; S2 += ssum2[j * 132 + tid]; }
        psum [(b * 64 + h) * 256 + ch + tid] = S;
        psum2[(b * 64 + h) * 256 + ch + tid] = S2;
    }
    const int c16 = tid & 15, w16 = tid >> 4;
#pragma unroll
    for (int p = 0; p < 4; ++p){
        int w = p * 16 + w16;
        union { ushort u[8]; uint4 v; } r;
#pragma unroll
        for (int j = 0; j < 8; ++j) r.u[j] = sh[(c16 * 8 + j) * 68 + w];
        size_t row = (size_t)(b * 4096 + h * 64 + w);
        *(uint4*)(xt + row * 256 + ch + c16 * 8) = r.v;
    }
}

// --------- P2: per-b scaled weights + folded bias + pad row (block-range) ---
__global__ __launch_bounds__(256)
void prep2(const float* __restrict__ Wq, const float* __restrict__ bq,
           const float* __restrict__ Wk, const float* __restrict__ bk,
           const float* __restrict__ Wv, const float* __restrict__ bv,
           const float* __restrict__ Wo,
           const float* __restrict__ psum, const float* __restrict__ psum2,
           ushort* __restrict__ wtq, ushort* __restrict__ wot,
           float* __restrict__ biasp, ushort* __restrict__ qkv){
    __shared__ float shW[32 * 33];
    __shared__ float shS[8 * 32], shS2[8 * 32], shRV[4 * 32], shM[256];
    __shared__ float shRed[4 * 256];
    const int bid = blockIdx.x, tid = threadIdx.x;
    if (bid < 192){
        int mat = bid / 64, tile = bid % 64;
        int ti = tile & 7, tj = tile >> 3;
        const float* src = (mat == 0) ? Wq : (mat == 1) ? Wk : Wv;
        float qs = (mat == 0) ? 0.0625f : 1.0f;
        int tx = tid & 31, ty = tid >> 5;
        float wreg[4];
#pragma unroll
        for (int i = 0; i < 4; ++i)
            wreg[i] = src[(size_t)(tj * 32 + ty + i * 8) * 256 + ti * 32 + tx] * qs;
        {
            int kk = tid & 31, idx = tid >> 5;        // idx: b*2 + h-half
            int b = idx >> 1, h0 = (idx & 1) * 32;
            float S = 0.f, S2 = 0.f;
#pragma unroll 8
            for (int r = 0; r < 32; ++r){
                int off = (b * 64 + h0 + r) * 256 + tj * 32 + kk;
                S += psum[off]; S2 += psum2[off];
            }
            shS[idx * 32 + kk] = S; shS2[idx * 32 + kk] = S2;
        }
        __syncthreads();
        if (tid < 128){
            int b = tid >> 5, kk = tid & 31;
            float S  = shS [(b * 2) * 32 + kk] + shS [(b * 2 + 1) * 32 + kk];
            float S2 = shS2[(b * 2) * 32 + kk] + shS2[(b * 2 + 1) * 32 + kk];
            float m = S * (1.f / 4096.f);
            float v = S2 * (1.f / 4096.f) - m * m;
            shRV[b * 32 + kk] = rsqrtf(v + 1e-5f);
        }
#pragma unroll
        for (int i = 0; i < 4; ++i)
            shW[(ty + i * 8) * 33 + tx] = wreg[i];
        __syncthreads();
#pragma unroll
        for (int b = 0; b < 4; ++b){
            float rv = shRV[b * 32 + tx];
#pragma unroll
            for (int i = 0; i < 4; ++i){
                int n = mat * 256 + ti * 32 + ty + i * 8;
                wtq[((size_t)b * 768 + n) * 256 + tj * 32 + tx] =
                    f2b(shW[tx * 33 + ty + i * 8] * rv);
            }
        }
    } else if (bid < 256){
        int tile = bid - 192;
        int ti = tile & 7, tj = tile >> 3;
        int tx = tid & 31, ty = tid >> 5;
#pragma unroll
        for (int i = 0; i < 4; ++i)
            shW[(ty + i * 8) * 33 + tx] =
                Wo[(size_t)(tj * 32 + ty + i * 8) * 256 + ti * 32 + tx];
        __syncthreads();
#pragma unroll
        for (int i = 0; i < 4; ++i)
            wot[(size_t)(ti * 32 + ty + i * 8) * 256 + tj * 32 + tx] =
                f2b(shW[tx * 33 + ty + i * 8]);
    } else if (bid < 268){
        int t = bid - 256;
        int b = t / 3, mat = t % 3;
        float S = 0.f, S2 = 0.f;
#pragma unroll 8
        for (int h = 0; h < 64; ++h){
            S += psum[(b * 64 + h) * 256 + tid]; S2 += psum2[(b * 64 + h) * 256 + tid];
        }
        float m = S * (1.f / 4096.f);
        float v = S2 * (1.f / 4096.f) - m * m;
        shM[tid] = m * rsqrtf(v + 1e-5f);
        __syncthreads();
        const float* W  = (mat == 0) ? Wq : (mat == 1) ? Wk : Wv;
        const float* bb = (mat == 0) ? bq : (mat == 1) ? bk : bv;
        float qs = (mat == 0) ? 0.0625f : 1.0f;
        const int wv = tid >> 6, l = tid & 63;
        float4 a4 = {0.f, 0.f, 0.f, 0.f};
#pragma unroll 8
        for (int i = 0; i < 64; ++i){
            int c = wv * 64 + i;
            float4 w4 = *(const float4*)(W + (size_t)c * 256 + l * 4);
            float s = shM[c];
            a4.x += s * w4.x; a4.y += s * w4.y;
            a4.z += s * w4.z; a4.w += s * w4.w;
        }
        *(float4*)&shRed[wv * 256 + l * 4] = a4;
        __syncthreads();
        float acc = shRed[tid] + shRed[256 + tid] + shRed[512 + tid] + shRed[768 + tid];
        biasp[b * 768 + mat * 256 + tid] = (bb[tid] - acc) * qs;
    } else {
        // pad row at qkv[NPIX]: q part zero, k = bf16(bk), v = bf16(bv)
        ushort* pad = qkv + (size_t)NPIX * QKVS;
        pad[tid]       = 0;
        pad[256 + tid] = f2b(bk[tid]);
        pad[512 + tid] = f2b(bv[tid]);
    }
}

// ---- QKV GEMM: 128x192 tile, BK=64, 8 waves, counted vmcnt, 512 blocks -----
__global__ __launch_bounds__(512, 4)
void gemm_qkv(const ushort* __restrict__ X, const ushort* __restrict__ Y,
              const float* __restrict__ bias, ushort* __restrict__ zb){
    __shared__ ushort ldsA[2][128 * 64];   // 32 KB
    __shared__ ushort ldsB[2][192 * 64];   // 48 KB
    const int tid  = threadIdx.x;
    const int lane = tid & 63;
    const int wid  = tid >> 6;            // 0..7
    const int wm   = wid >> 2;            // 0..1 : rows wm*64
    const int wn   = wid & 3;             // 0..3 : cols wn*48
    const int tile  = (blockIdx.x & 7) * 64 + (blockIdx.x >> 3);  // XCD swizzle
    const int mtile = tile >> 2, ntile = tile & 3;                // ntile fastest
    const int x0 = mtile * 128, y0 = ntile * 192;
    const int bsel = x0 >> 12;
    const ushort* Yb   = Y + ((size_t)bsel * QKVS + y0) * 256;
    const float* biasb = bias + bsel * QKVS;

    auto stage = [&](int buf, int k0){
#pragma unroll
        for (int i = 0; i < 2; ++i){
            int f   = i * 512 + tid;          // A chunk 0..1023
            int row = f >> 3, cp = f & 7;
            int cs  = cp ^ (row & 7);
            const ushort* ga = X + (size_t)(x0 + row) * KDIM + k0 + cs * 8;
            __builtin_amdgcn_global_load_lds(
                (const __attribute__((address_space(1))) void*)ga,
                (__attribute__((address_space(3))) void*)&ldsA[buf][f * 8], 16, 0, 0);
        }
#pragma unroll
        for (int i = 0; i < 3; ++i){
            int f   = i * 512 + tid;          // B chunk 0..1535
            int row = f >> 3, cp = f & 7;
            int cs  = cp ^ (row & 7);
            const ushort* gb = Yb + (size_t)row * KDIM + k0 + cs * 8;
            __builtin_amdgcn_global_load_lds(
                (const __attribute__((address_space(1))) void*)gb,
                (__attribute__((address_space(3))) void*)&ldsB[buf][f * 8], 16, 0, 0);
        }
    };

    f32x4 acc[4][3];
#pragma unroll
    for (int i = 0; i < 4; ++i)
#pragma unroll
        for (int j = 0; j < 3; ++j) acc[i][j] = f32x4{0.f, 0.f, 0.f, 0.f};

    stage(0, 0);
    stage(1, 64);
#pragma unroll
    for (int t = 0; t < 4; ++t){
        if (t < 3) asm volatile("s_waitcnt vmcnt(5)" ::: "memory");
        else       asm volatile("s_waitcnt vmcnt(0)" ::: "memory");
        __builtin_amdgcn_sched_barrier(0);
        __builtin_amdgcn_s_barrier();
        __builtin_amdgcn_sched_barrier(0);
        const int buf = t & 1;
        __builtin_amdgcn_s_setprio(1);
#pragma unroll
        for (int kk = 0; kk < 2; ++kk){
            bf16x8 af[4], bf[3];
#pragma unroll
            for (int fm = 0; fm < 4; ++fm){
                int r = wm * 64 + fm * 16 + (lane & 15);
                int c = kk * 4 + (lane >> 4);
                af[fm] = *(const bf16x8*)&ldsA[buf][(r * 8 + (c ^ (r & 7))) * 8];
            }
#pragma unroll
            for (int fn = 0; fn < 3; ++fn){
                int r = wn * 48 + fn * 16 + (lane & 15);
                int c = kk * 4 + (lane >> 4);
                bf[fn] = *(const bf16x8*)&ldsB[buf][(r * 8 + (c ^ (r & 7))) * 8];
            }
#pragma unroll
            for (int fm = 0; fm < 4; ++fm)
#pragma unroll
                for (int fn = 0; fn < 3; ++fn)
                    acc[fm][fn] = __builtin_amdgcn_mfma_f32_16x16x32_bf16(
                        af[fm], bf[fn], acc[fm][fn], 0, 0, 0);
        }
        __builtin_amdgcn_s_setprio(0);
        __builtin_amdgcn_sched_barrier(0);
        __builtin_amdgcn_s_barrier();
        __builtin_amdgcn_sched_barrier(0);
        if (t < 2) stage(t & 1, (t + 2) * 64);
    }

#pragma unroll
    for (int fm = 0; fm < 4; ++fm){
#pragma unroll
        for (int fn = 0; fn < 3; ++fn){
            int xr = x0 + wm * 64 + fm * 16 + ((lane >> 4) << 2);
            int yc = y0 + wn * 48 + fn * 16 + (lane & 15);
            float bv = biasb[yc];
#pragma unroll
            for (int r = 0; r < 4; ++r)
                zb[(size_t)(xr + r) * QKVS + yc] = f2b(acc[fm][fn][r] + bv);
        }
    }
}

// --------- 3x3 window attention: LDS-staged 6x6 K/V window per 4x4 tile -----
// stage: 36 rows x 512B (k|v) via global_load_lds (each wave = one row),
// row stride 520 ushorts (bank shift 4/row). Per-pixel reads hit LDS.
__global__ __launch_bounds__(256)
void attn_win(const ushort* __restrict__ qkv, ushort* __restrict__ ctx){
    __shared__ ushort kv[36 * KVROW];
    const int tid = threadIdx.x;
    const int lane = tid & 63, wid = tid >> 6;
    const int l16 = lane & 15, pg = lane >> 4;
    const int obid = (blockIdx.x & 7) * 128 + (blockIdx.x >> 3);  // XCD swizzle
    const int t = obid & 255, b = obid >> 8;
    const int tr = t >> 4, tc = t & 15;
    const int p = wid * 4 + pg;               // pixel 0..15 within tile
    const int pr = p >> 2, pc = p & 3;
    const int h = tr * 4 + pr, w = tc * 4 + pc;
    const int pix = (b << 12) + (h << 6) + w;
    const uint PADOFF = (uint)NPIX * QKVS;
    const int cbase = l16 * 16;

    // ---- stage the 6x6-row k/v window union (36 rows x 64 16B-chunks) ----
#pragma unroll
    for (int i = 0; i < 9; ++i){
        int chunk = i * 256 + tid;            // 0..2303
        int row36 = chunk >> 6, sub = chunk & 63;
        int rr = row36 / 6, cc = row36 - rr * 6;
        int nh = tr * 4 + rr - 1, nw = tc * 4 + cc - 1;
        bool ok = ((unsigned)nh < 64u) & ((unsigned)nw < 64u);
        uint roww = ok ? (uint)(((b << 12) + (nh << 6) + nw) * QKVS) : PADOFF;
        const ushort* g = qkv + roww + 256 + sub * 8;   // k|v contiguous
        __builtin_amdgcn_global_load_lds(
            (const __attribute__((address_space(1))) void*)g,
            (__attribute__((address_space(3))) void*)&kv[row36 * KVROW + sub * 8],
            16, 0, 0);
    }

    // q for own pixel (global, independent of staging)
    const ushort* qp = qkv + (size_t)pix * QKVS + cbase;
    uint4 qa = *(const uint4*)qp;
    uint4 qb = *(const uint4*)(qp + 8);
    float qf[16];
    unpack2(qa.x, qf[0], qf[1]);  unpack2(qa.y, qf[2], qf[3]);
    unpack2(qa.z, qf[4], qf[5]);  unpack2(qa.w, qf[6], qf[7]);
    unpack2(qb.x, qf[8], qf[9]);  unpack2(qb.y, qf[10], qf[11]);
    unpack2(qb.z, qf[12], qf[13]); unpack2(qb.w, qf[14], qf[15]);

    asm volatile("s_waitcnt vmcnt(0)" ::: "memory");
    __syncthreads();

    float lg[9];
#pragma unroll
    for (int n = 0; n < 9; ++n){
        int row36 = (pr + n / 3) * 6 + (pc + n % 3);
        const ushort* kp = &kv[row36 * KVROW + cbase];
        uint4 ka = *(const uint4*)kp;
        uint4 kb = *(const uint4*)(kp + 8);
        float kf[16];
        unpack2(ka.x, kf[0], kf[1]);  unpack2(ka.y, kf[2], kf[3]);
        unpack2(ka.z, kf[4], kf[5]);  unpack2(ka.w, kf[6], kf[7]);
        unpack2(kb.x, kf[8], kf[9]);  unpack2(kb.y, kf[10], kf[11]);
        unpack2(kb.z, kf[12], kf[13]); unpack2(kb.w, kf[14], kf[15]);
        float d = 0.f;
#pragma unroll
        for (int j = 0; j < 16; ++j) d += qf[j] * kf[j];
        d += __shfl_xor(d, 1); d += __shfl_xor(d, 2);
        d += __shfl_xor(d, 4); d += __shfl_xor(d, 8);
        lg[n] = d;
    }
    float m = lg[0];
#pragma unroll
    for (int n = 1; n < 9; ++n) m = fmaxf(m, lg[n]);
    float e[9], s = 0.f;
#pragma unroll
    for (int n = 0; n < 9; ++n){ e[n] = __expf(lg[n] - m); s += e[n]; }
    float inv = 1.f / s;

    float c[16];
#pragma unroll
    for (int j = 0; j < 16; ++j) c[j] = 0.f;
#pragma unroll
    for (int n = 0; n < 9; ++n){
        float a = e[n] * inv;
        int row36 = (pr + n / 3) * 6 + (pc + n % 3);
        const ushort* vp = &kv[row36 * KVROW + 256 + cbase];
        uint4 va = *(const uint4*)vp;
        uint4 vb = *(const uint4*)(vp + 8);
        float vf[16];
        unpack2(va.x, vf[0], vf[1]);  unpack2(va.y, vf[2], vf[3]);
        unpack2(va.z, vf[4], vf[5]);  unpack2(va.w, vf[6], vf[7]);
        unpack2(vb.x, vf[8], vf[9]);  unpack2(vb.y, vf[10], vf[11]);
        unpack2(vb.z, vf[12], vf[13]); unpack2(vb.w, vf[14], vf[15]);
#pragma unroll
        for (int j = 0; j < 16; ++j) c[j] += a * vf[j];
    }
    uint4 oa, ob;
    oa.x = cvtpk(c[0], c[1]);   oa.y = cvtpk(c[2], c[3]);
    oa.z = cvtpk(c[4], c[5]);   oa.w = cvtpk(c[6], c[7]);
    ob.x = cvtpk(c[8], c[9]);   ob.y = cvtpk(c[10], c[11]);
    ob.z = cvtpk(c[12], c[13]); ob.w = cvtpk(c[14], c[15]);
    ushort* op = ctx + (size_t)pix * 256 + cbase;
    *(uint4*)op = oa;
    *(uint4*)(op + 8) = ob;
}

// ------------- out GEMM (128x128, NCHW fp32 epilogue, XCD pair swizzle) -----
__global__ __launch_bounds__(256, 2)
void gemm_out(const ushort* __restrict__ X, const ushort* __restrict__ Y,
              const float* __restrict__ bias, float* __restrict__ zf){
    __shared__ ushort ldsX[2][128 * 64];
    __shared__ ushort ldsY[2][128 * 64];
    const int tid  = threadIdx.x;
    const int lane = tid & 63;
    const int wid  = tid >> 6;
    const int wm   = wid >> 1, wn = wid & 1;
    const int tile = (blockIdx.x & 7) * 32 + (blockIdx.x >> 3);
    const int x0   = (tile & 1) * 128;    // ch tile (2)
    const int y0   = (tile >> 1) * 128;   // pixel tile (128)

    auto stage = [&](int buf, int k0){
#pragma unroll
        for (int i = 0; i < 4; ++i){
            int f   = i * 256 + tid;
            int row = f >> 3, cp = f & 7;
            int cs  = cp ^ (row & 7);
            const ushort* gx = X + (size_t)(x0 + row) * KDIM + k0 + cs * 8;
            const ushort* gy = Y + (size_t)(y0 + row) * KDIM + k0 + cs * 8;
            __builtin_amdgcn_global_load_lds(
                (const __attribute__((address_space(1))) void*)gx,
                (__attribute__((address_space(3))) void*)&ldsX[buf][f * 8], 16, 0, 0);
            __builtin_amdgcn_global_load_lds(
                (const __attribute__((address_space(1))) void*)gy,
                (__attribute__((address_space(3))) void*)&ldsY[buf][f * 8], 16, 0, 0);
        }
    };

    f32x4 acc[4][4];
#pragma unroll
    for (int i = 0; i < 4; ++i)
#pragma unroll
        for (int j = 0; j < 4; ++j) acc[i][j] = f32x4{0.f, 0.f, 0.f, 0.f};

    stage(0, 0);
    int buf = 0;
    for (int t = 0; t < 4; ++t){
        __syncthreads();
        if (t < 3) stage(buf ^ 1, (t + 1) * 64);
#pragma unroll
        for (int kk = 0; kk < 2; ++kk){
            bf16x8 xa[4], yb[4];
#pragma unroll
            for (int fm = 0; fm < 4; ++fm){
                int r = wm * 64 + fm * 16 + (lane & 15);
                int c = kk * 4 + (lane >> 4);
                xa[fm] = *(const bf16x8*)&ldsX[buf][(r * 8 + (c ^ (r & 7))) * 8];
            }
#pragma unroll
            for (int fn = 0; fn < 4; ++fn){
                int r = wn * 64 + fn * 16 + (lane & 15);
                int c = kk * 4 + (lane >> 4);
                yb[fn] = *(const bf16x8*)&ldsY[buf][(r * 8 + (c ^ (r & 7))) * 8];
            }
#pragma unroll
            for (int fm = 0; fm < 4; ++fm)
#pragma unroll
                for (int fn = 0; fn < 4; ++fn)
                    acc[fm][fn] = __builtin_amdgcn_mfma_f32_16x16x32_bf16(
                        xa[fm], yb[fn], acc[fm][fn], 0, 0, 0);
        }
        buf ^= 1;
    }

#pragma unroll
    for (int fm = 0; fm < 4; ++fm){
#pragma unroll
        for (int fn = 0; fn < 4; ++fn){
            int xr = x0 + wm * 64 + fm * 16 + ((lane >> 4) << 2);
            int yc = y0 + wn * 64 + fn * 16 + (lane & 15);
            int bpix = yc >> 12, hw = yc & 4095;
#pragma unroll
            for (int r = 0; r < 4; ++r){
                int ch = xr + r;
                zf[((size_t)(bpix * 256 + ch)) * 4096 + hw] =
                    acc[fm][fn][r] + bias[ch];
            }
        }
    }
}

// ---------------------------------------------------------------------------
extern "C" void kernel_launch(void* const* d_in, const int* in_sizes, int n_in,
                              void* d_out, int out_size, void* d_ws, size_t ws_size,
                              hipStream_t stream){
    const float* x  = (const float*)d_in[0];
    const float* Wq = (const float*)d_in[1];
    const float* bq = (const float*)d_in[2];
    const float* Wk = (const float*)d_in[3];
    const float* bk = (const float*)d_in[4];
    const float* Wv = (const float*)d_in[5];
    const float* bv = (const float*)d_in[6];
    const float* Wo = (const float*)d_in[7];
    const float* bo = (const float*)d_in[8];
    float* out = (float*)d_out;

    char* ws = (char*)d_ws;
    ushort* wtq    = (ushort*)(ws);                // [4][768][256] bf16
    ushort* wot    = (ushort*)(ws + 1572864);      // [256][256] bf16
    float*  biasp  = (float*) (ws + 1703936);      // [4][768]
    float*  psum   = (float*) (ws + 1716224);      // [256][256]
    float*  psum2  = (float*) (ws + 1978368);      // [256][256]
    ushort* xt     = (ushort*)(ws + 2240512);      // [NPIX][256] bf16
    ushort* qkv    = (ushort*)(ws + 10629120);     // [NPIX+1][768] bf16 (+pad row)
    ushort* ctx    = (ushort*)(ws + 35796480);     // [NPIX][256] bf16

    ln_fuse<<<512, 256, 0, stream>>>(x, xt, psum, psum2);
    prep2<<<269, 256, 0, stream>>>(Wq, bq, Wk, bk, Wv, bv, Wo,
                                   psum, psum2, wtq, wot, biasp, qkv);

    gemm_qkv<<<512, 512, 0, stream>>>(xt, wtq, biasp, qkv);   // 128 M x 4 N tiles

    attn_win<<<1024, 256, 0, stream>>>(qkv, ctx);

    gemm_out<<<256, 256, 0, stream>>>(wot, ctx, bo, out);
}